// Round 8
// baseline (2176.214 us; speedup 1.0000x reference)
//
#include <hip/hip_runtime.h>
#include <math.h>

#define NN   40000
#define EE   640000
#define HID  32
#define FEAT 16
#define LAB  4
#define TT   8
#define DIN  53   // FEAT + LAB + HID + 1
#define WD   (HID * DIN)

// ---------------- bf16 helpers (storage-only; math stays f32) --------------

__device__ __forceinline__ unsigned short f2bf(float f) {
    unsigned int u = __float_as_uint(f);
    unsigned int r = u + 0x7fffu + ((u >> 16) & 1u);   // RNE
    return (unsigned short)(r >> 16);
}
__device__ __forceinline__ float bflo(unsigned int u) { return __uint_as_float(u << 16); }
__device__ __forceinline__ float bfhi(unsigned int u) { return __uint_as_float(u & 0xffff0000u); }
__device__ __forceinline__ void unpack8(uint4 u, float* v) {
    v[0] = bflo(u.x); v[1] = bfhi(u.x);
    v[2] = bflo(u.y); v[3] = bfhi(u.y);
    v[4] = bflo(u.z); v[5] = bfhi(u.z);
    v[6] = bflo(u.w); v[7] = bfhi(u.w);
}

// ---------------- CSR build ----------------

__global__ __launch_bounds__(256) void zero_i32(int* __restrict__ p, int n) {
    int i = blockIdx.x * 256 + threadIdx.x;
    if (i < n) p[i] = 0;
}

__global__ __launch_bounds__(256) void hist_kernel(const int* __restrict__ dst,
                                                   int* __restrict__ deg) {
    int e = blockIdx.x * 256 + threadIdx.x;
    if (e < EE) atomicAdd(&deg[dst[e]], 1);
}

__global__ __launch_bounds__(1024) void scan_kernel(const int* __restrict__ deg,
                                                    int* __restrict__ row_ptr) {
    __shared__ int wsum[16];
    __shared__ int chunk_total;
    int tid = threadIdx.x;
    int lane = tid & 63, wv = tid >> 6;
    int carry = 0;
    if (tid == 0) row_ptr[0] = 0;
    for (int base = 0; base < NN; base += 1024) {
        int i = base + tid;
        int v = (i < NN) ? deg[i] : 0;
        #pragma unroll
        for (int o = 1; o < 64; o <<= 1) {
            int t = __shfl_up(v, o);
            if (lane >= o) v += t;
        }
        if (lane == 63) wsum[wv] = v;
        __syncthreads();
        if (tid < 16) {
            int s = wsum[tid];
            #pragma unroll
            for (int o = 1; o < 16; o <<= 1) {
                int t = __shfl_up(s, o);
                if (tid >= o) s += t;
            }
            wsum[tid] = s;
            if (tid == 15) chunk_total = s;
        }
        __syncthreads();
        int woff = (wv == 0) ? 0 : wsum[wv - 1];
        if (i < NN) row_ptr[i + 1] = carry + woff + v;
        carry += chunk_total;
        __syncthreads();
    }
}

__global__ __launch_bounds__(256) void scatter_kernel(const int* __restrict__ src,
                                                      const int* __restrict__ dst,
                                                      const int* __restrict__ row_ptr,
                                                      int* __restrict__ cursor,
                                                      int* __restrict__ csr_src) {
    int e = blockIdx.x * 256 + threadIdx.x;
    if (e < EE) {
        int d = dst[e];
        int pos = atomicAdd(&cursor[d], 1);
        csr_src[row_ptr[d] + pos] = src[e];
    }
}

// canonicalize: sort each node's segment ascending -> csr_src becomes a pure
// function of the inputs (atomicAdd ordering no longer observable) -> every
// call is bit-identical (graph-replay same-work invariant).
__global__ __launch_bounds__(256) void sort_kernel(const int* __restrict__ row_ptr,
                                                   int* __restrict__ csr_src) {
    int n = blockIdx.x * 256 + threadIdx.x;
    if (n < NN) {
        int beg = row_ptr[n], end = row_ptr[n + 1];
        for (int i = beg + 1; i < end; ++i) {
            int key = csr_src[i];
            int j = i - 1;
            while (j >= beg && csr_src[j] > key) {
                csr_src[j + 1] = csr_src[j];
                --j;
            }
            csr_src[j + 1] = key;
        }
    }
}

// ---------------- state init ----------------

__global__ __launch_bounds__(256) void init_kernel(const float* __restrict__ x0,
                                                   const float* __restrict__ mask,
                                                   float* __restrict__ hidden,
                                                   float* __restrict__ x2) {
    int i = blockIdx.x * 256 + threadIdx.x;
    if (i < NN * HID) hidden[i] = 1.0f;
    if (i < NN * FEAT) {
        int node = i >> 4;
        x2[i] = (mask[node] > 0.5f) ? x0[i] : 0.0f;
    }
}

// ---------------- dense01: both sigmoid-gate projections, 8 nodes/block ----
// inp = [feat16, mask, labels4, h32]; xl packed bf16 [node][gate][32]

__global__ __launch_bounds__(256) void dense01_kernel(const float* __restrict__ feat,
                                                      const float* __restrict__ mask,
                                                      const float* __restrict__ labels,
                                                      const float* __restrict__ hsrc,
                                                      const float* __restrict__ Wl,
                                                      const float* __restrict__ bl,
                                                      const float* __restrict__ Wr,
                                                      const float* __restrict__ br,
                                                      unsigned short* __restrict__ xl01h,
                                                      float* __restrict__ xr01) {
    __shared__ float W_s[4 * WD];     // Wl0 | Wl1 | Wr0 | Wr1
    __shared__ float inp_s[8][DIN];
    for (int idx = threadIdx.x; idx < WD; idx += 256) {
        W_s[idx]          = Wl[idx];
        W_s[WD + idx]     = Wl[WD + idx];
        W_s[2 * WD + idx] = Wr[idx];
        W_s[3 * WD + idx] = Wr[WD + idx];
    }
    int ni = threadIdx.x >> 5, k = threadIdx.x & 31;
    int node = blockIdx.x * 8 + ni;
    for (int i = k; i < DIN; i += 32) {
        float v;
        if (i < 16)       v = feat[node * 16 + i];
        else if (i == 16) v = mask[node];
        else if (i < 21)  v = labels[node * 4 + (i - 17)];
        else              v = hsrc[node * 32 + (i - 21)];
        inp_s[ni][i] = v;
    }
    __syncthreads();
    float l0 = bl[k], l1 = bl[HID + k], r0 = br[k], r1 = br[HID + k];
    const float* w0 = &W_s[k * DIN];
    const float* w1 = &W_s[WD + k * DIN];
    const float* w2 = &W_s[2 * WD + k * DIN];
    const float* w3 = &W_s[3 * WD + k * DIN];
#pragma unroll
    for (int i = 0; i < DIN; ++i) {
        float xv = inp_s[ni][i];
        l0 += xv * w0[i];
        l1 += xv * w1[i];
        r0 += xv * w2[i];
        r1 += xv * w3[i];
    }
    xl01h[node * 64 + k]      = f2bf(l0);
    xl01h[node * 64 + 32 + k] = f2bf(l1);
    xr01[node * 64 + k]      = r0;
    xr01[node * 64 + 32 + k] = r1;
}

// ---------------- dense (cell gate), 8 nodes/block -------------------------
// inp = [feat16, mask, labels4, h32 * hmul]; xl packed bf16

__global__ __launch_bounds__(256) void dense_kernel(const float* __restrict__ feat,
                                                    const float* __restrict__ mask,
                                                    const float* __restrict__ labels,
                                                    const float* __restrict__ hsrc,
                                                    const float* __restrict__ hmul,
                                                    const float* __restrict__ Wl,
                                                    const float* __restrict__ bl,
                                                    const float* __restrict__ Wr,
                                                    const float* __restrict__ br,
                                                    unsigned short* __restrict__ xlh,
                                                    float* __restrict__ xr) {
    __shared__ float Wl_s[WD];
    __shared__ float Wr_s[WD];
    __shared__ float inp_s[8][DIN];
    for (int idx = threadIdx.x; idx < WD; idx += 256) {
        Wl_s[idx] = Wl[idx];
        Wr_s[idx] = Wr[idx];
    }
    int ni = threadIdx.x >> 5, k = threadIdx.x & 31;
    int node = blockIdx.x * 8 + ni;
    for (int i = k; i < DIN; i += 32) {
        float v;
        if (i < 16)       v = feat[node * 16 + i];
        else if (i == 16) v = mask[node];
        else if (i < 21)  v = labels[node * 4 + (i - 17)];
        else              v = hsrc[node * 32 + (i - 21)] * hmul[node * 32 + (i - 21)];
        inp_s[ni][i] = v;
    }
    __syncthreads();
    float al = bl[k], ar = br[k];
    const float* wlr = &Wl_s[k * DIN];
    const float* wrr = &Wr_s[k * DIN];
#pragma unroll
    for (int i = 0; i < DIN; ++i) {
        float xv = inp_s[ni][i];
        al += xv * wlr[i];
        ar += xv * wrr[i];
    }
    xlh[node * 32 + k] = f2bf(al);
    xr[node * 32 + k] = ar;
}

// -------- conv helpers (one node per 64-lane wave, 16 groups x 4 lanes) ----

__device__ __forceinline__ float edge_score8(const float* v, const float* xr, const float* at) {
    float part = 0.0f;
#pragma unroll
    for (int i = 0; i < 8; ++i) {
        float z = v[i] + xr[i];
        z = (z > 0.0f) ? z : 0.2f * z;
        part += z * at[i];
    }
    part += __shfl_xor(part, 1);
    part += __shfl_xor(part, 2);
    return part;
}

__device__ __forceinline__ void online_update8(float e, float& m, float& den, float* acc,
                                               const float* v) {
    if (e > m) {
        float sc = __expf(m - e);
        den *= sc;
#pragma unroll
        for (int i = 0; i < 8; ++i) acc[i] *= sc;
        m = e;
    }
    float a = __expf(e - m);
    den += a;
#pragma unroll
    for (int i = 0; i < 8; ++i) acc[i] += a * v[i];
}

// merge across 16 groups (full wave; masks 4,8,16,32)
__device__ __forceinline__ void merge_full(float m, float den, const float* acc,
                                           bool ne, float* o) {
    if (ne) {
        float mt = m;
        mt = fmaxf(mt, __shfl_xor(mt, 4));
        mt = fmaxf(mt, __shfl_xor(mt, 8));
        mt = fmaxf(mt, __shfl_xor(mt, 16));
        mt = fmaxf(mt, __shfl_xor(mt, 32));
        float sc = __expf(m - mt);          // empty group: exp(-inf) = 0
        float d = den * sc;
        d += __shfl_xor(d, 4);
        d += __shfl_xor(d, 8);
        d += __shfl_xor(d, 16);
        d += __shfl_xor(d, 32);
#pragma unroll
        for (int i = 0; i < 8; ++i) {
            float t = acc[i] * sc;
            t += __shfl_xor(t, 4);
            t += __shfl_xor(t, 8);
            t += __shfl_xor(t, 16);
            t += __shfl_xor(t, 32);
            o[i] = t / d;                    // d >= 1 (max group contributes 1)
        }
    } else {
#pragma unroll
        for (int i = 0; i < 8; ++i) o[i] = 0.0f;
    }
}

// ---------------- conv01: both sigmoid gates in one CSR walk (full wave) ---
// bf16 xl gather: 2 x 16B loads from one 128B row per edge.

__global__ __launch_bounds__(256) void conv01_kernel(const int* __restrict__ row_ptr,
                                                     const int* __restrict__ csr_src,
                                                     const unsigned short* __restrict__ xl01h,
                                                     const float* __restrict__ xr01,
                                                     const float* __restrict__ att,
                                                     const float* __restrict__ bconv,
                                                     float* __restrict__ g0,
                                                     float* __restrict__ g1) {
    int wid  = threadIdx.x >> 6;
    int lane = threadIdx.x & 63;
    int g = lane >> 2, j = lane & 3;
    int n = blockIdx.x * 4 + wid;
    int c0 = j * 8;
    int beg = row_ptr[n], end = row_ptr[n + 1];

    float at0v[8], at1v[8], xr0v[8], xr1v[8];
    {
        float4 a0 = *(const float4*)(att + c0);
        float4 a1 = *(const float4*)(att + c0 + 4);
        at0v[0] = a0.x; at0v[1] = a0.y; at0v[2] = a0.z; at0v[3] = a0.w;
        at0v[4] = a1.x; at0v[5] = a1.y; at0v[6] = a1.z; at0v[7] = a1.w;
        float4 b0 = *(const float4*)(att + 32 + c0);
        float4 b1 = *(const float4*)(att + 32 + c0 + 4);
        at1v[0] = b0.x; at1v[1] = b0.y; at1v[2] = b0.z; at1v[3] = b0.w;
        at1v[4] = b1.x; at1v[5] = b1.y; at1v[6] = b1.z; at1v[7] = b1.w;
        const float* xrn = xr01 + n * 64;
        float4 r0 = *(const float4*)(xrn + c0);
        float4 r1 = *(const float4*)(xrn + c0 + 4);
        xr0v[0] = r0.x; xr0v[1] = r0.y; xr0v[2] = r0.z; xr0v[3] = r0.w;
        xr0v[4] = r1.x; xr0v[5] = r1.y; xr0v[6] = r1.z; xr0v[7] = r1.w;
        float4 r2 = *(const float4*)(xrn + 32 + c0);
        float4 r3 = *(const float4*)(xrn + 32 + c0 + 4);
        xr1v[0] = r2.x; xr1v[1] = r2.y; xr1v[2] = r2.z; xr1v[3] = r2.w;
        xr1v[4] = r3.x; xr1v[5] = r3.y; xr1v[6] = r3.z; xr1v[7] = r3.w;
    }

    float m0 = -INFINITY, den0 = 0.0f, acc0[8] = {0, 0, 0, 0, 0, 0, 0, 0};
    float m1 = -INFINITY, den1 = 0.0f, acc1[8] = {0, 0, 0, 0, 0, 0, 0, 0};

    for (int p = beg + g; p < end; p += 16) {
        int s = csr_src[p];
        const unsigned short* row = xl01h + (size_t)s * 64;
        uint4 u0 = *(const uint4*)(row + c0);
        uint4 u1 = *(const uint4*)(row + 32 + c0);
        float v0[8], v1[8];
        unpack8(u0, v0);
        unpack8(u1, v1);
        float e0 = edge_score8(v0, xr0v, at0v);
        float e1 = edge_score8(v1, xr1v, at1v);
        online_update8(e0, m0, den0, acc0, v0);
        online_update8(e1, m1, den1, acc1, v1);
    }

    float o0[8], o1[8];
    bool ne = beg < end;
    merge_full(m0, den0, acc0, ne, o0);
    merge_full(m1, den1, acc1, ne, o1);

    if (g == 0) {
        const float* bc0 = bconv + c0;
        const float* bc1 = bconv + 32 + c0;
        float r0[8], r1[8];
#pragma unroll
        for (int i = 0; i < 8; ++i) {
            r0[i] = 1.0f / (1.0f + __expf(-(o0[i] + bc0[i])));
            r1[i] = 1.0f / (1.0f + __expf(-(o1[i] + bc1[i])));
        }
        float* p0 = g0 + n * 32 + c0;
        ((float4*)p0)[0] = make_float4(r0[0], r0[1], r0[2], r0[3]);
        ((float4*)p0)[1] = make_float4(r0[4], r0[5], r0[6], r0[7]);
        float* p1 = g1 + n * 32 + c0;
        ((float4*)p1)[0] = make_float4(r1[0], r1[1], r1[2], r1[3]);
        ((float4*)p1)[1] = make_float4(r1[4], r1[5], r1[6], r1[7]);
    }
}

// ---------------- conv2 (cell gate, tanh): full wave, bf16 gather ----------

__global__ __launch_bounds__(256) void conv2_kernel(const int* __restrict__ row_ptr,
                                                    const int* __restrict__ csr_src,
                                                    const unsigned short* __restrict__ xlh,
                                                    const float* __restrict__ xr,
                                                    const float* __restrict__ att,
                                                    const float* __restrict__ bconv,
                                                    float* __restrict__ out) {
    int wid  = threadIdx.x >> 6;
    int lane = threadIdx.x & 63;
    int g = lane >> 2, j = lane & 3;
    int n = blockIdx.x * 4 + wid;
    int c0 = j * 8;
    int beg = row_ptr[n], end = row_ptr[n + 1];

    float at[8], xrv[8];
    {
        float4 a0 = *(const float4*)(att + c0);
        float4 a1 = *(const float4*)(att + c0 + 4);
        at[0] = a0.x; at[1] = a0.y; at[2] = a0.z; at[3] = a0.w;
        at[4] = a1.x; at[5] = a1.y; at[6] = a1.z; at[7] = a1.w;
        float4 r0 = *(const float4*)(xr + n * 32 + c0);
        float4 r1 = *(const float4*)(xr + n * 32 + c0 + 4);
        xrv[0] = r0.x; xrv[1] = r0.y; xrv[2] = r0.z; xrv[3] = r0.w;
        xrv[4] = r1.x; xrv[5] = r1.y; xrv[6] = r1.z; xrv[7] = r1.w;
    }

    float m = -INFINITY, den = 0.0f, acc[8] = {0, 0, 0, 0, 0, 0, 0, 0};
    for (int p = beg + g; p < end; p += 16) {
        int s = csr_src[p];
        uint4 u = *(const uint4*)(xlh + (size_t)s * 32 + c0);
        float v[8];
        unpack8(u, v);
        float e = edge_score8(v, xrv, at);
        online_update8(e, m, den, acc, v);
    }
    float o[8];
    merge_full(m, den, acc, beg < end, o);

    if (g == 0) {
        const float* bc = bconv + c0;
        float r[8];
#pragma unroll
        for (int i = 0; i < 8; ++i) r[i] = tanhf(o[i] + bc[i]);
        float* op = out + n * 32 + c0;
        ((float4*)op)[0] = make_float4(r[0], r[1], r[2], r[3]);
        ((float4*)op)[1] = make_float4(r[4], r[5], r[6], r[7]);
    }
}

// ---------------- conv3 + y2/x2/out fused, bf16 gather ---------------------

__global__ __launch_bounds__(256) void conv3_out_kernel(const int* __restrict__ row_ptr,
                                                        const int* __restrict__ csr_src,
                                                        const unsigned short* __restrict__ xlh,
                                                        const float* __restrict__ xr,
                                                        const float* __restrict__ att,
                                                        const float* __restrict__ bconv,
                                                        const float* __restrict__ hidden,
                                                        const float* __restrict__ W2,
                                                        const float* __restrict__ b2,
                                                        const float* __restrict__ x_t,
                                                        const float* __restrict__ mask,
                                                        float* __restrict__ x2,
                                                        float* __restrict__ out_t) {
    __shared__ float W2s[64 * 16];   // transposed [c][f]
    for (int idx = threadIdx.x; idx < 64 * 16; idx += 256) {
        int f = idx & 15, c = idx >> 4;
        W2s[c * 16 + f] = W2[f * 64 + c];
    }
    __syncthreads();

    int wid  = threadIdx.x >> 6;
    int lane = threadIdx.x & 63;
    int g = lane >> 2, j = lane & 3;
    int n = blockIdx.x * 4 + wid;
    int c0 = j * 8;
    int beg = row_ptr[n], end = row_ptr[n + 1];

    float at[8], xrv[8];
    {
        float4 a0 = *(const float4*)(att + c0);
        float4 a1 = *(const float4*)(att + c0 + 4);
        at[0] = a0.x; at[1] = a0.y; at[2] = a0.z; at[3] = a0.w;
        at[4] = a1.x; at[5] = a1.y; at[6] = a1.z; at[7] = a1.w;
        float4 r0 = *(const float4*)(xr + n * 32 + c0);
        float4 r1 = *(const float4*)(xr + n * 32 + c0 + 4);
        xrv[0] = r0.x; xrv[1] = r0.y; xrv[2] = r0.z; xrv[3] = r0.w;
        xrv[4] = r1.x; xrv[5] = r1.y; xrv[6] = r1.z; xrv[7] = r1.w;
    }

    float m = -INFINITY, den = 0.0f, acc[8] = {0, 0, 0, 0, 0, 0, 0, 0};
    for (int p = beg + g; p < end; p += 16) {
        int s = csr_src[p];
        uint4 u = *(const uint4*)(xlh + (size_t)s * 32 + c0);
        float v[8];
        unpack8(u, v);
        float e = edge_score8(v, xrv, at);
        online_update8(e, m, den, acc, v);
    }
    float o[8];
    merge_full(m, den, acc, beg < end, o);

    // s (relu), j-sliced, in all lanes
    float r[8], hv[8];
    {
        const float* bc = bconv + c0;
#pragma unroll
        for (int i = 0; i < 8; ++i) r[i] = fmaxf(o[i] + bc[i], 0.0f);
        float4 h0 = *(const float4*)(hidden + n * 32 + c0);
        float4 h1 = *(const float4*)(hidden + n * 32 + c0 + 4);
        hv[0] = h0.x; hv[1] = h0.y; hv[2] = h0.z; hv[3] = h0.w;
        hv[4] = h1.x; hv[5] = h1.y; hv[6] = h1.z; hv[7] = h1.w;
    }

    int f = lane & 15;
    int base = lane & ~3;
    float y = b2[f];
#pragma unroll
    for (int j2 = 0; j2 < 4; ++j2) {
#pragma unroll
        for (int i = 0; i < 8; ++i) {
            float sv = __shfl(r[i], base + j2);
            float hh = __shfl(hv[i], base + j2);
            int c = j2 * 8 + i;
            y += sv * W2s[c * 16 + f] + hh * W2s[(32 + c) * 16 + f];
        }
    }
    if (lane < 16) {
        float mv = mask[n];
        float xv = x_t[n * 16 + f];
        float rr = (mv > 0.5f) ? xv : y;
        x2[n * 16 + f] = rr;
        out_t[n * 16 + f] = rr;
    }
}

// ---------------- hidden update + y1/x1 + dense3, 8 nodes/block ------------
// ft2 = [x1(0..15), mask(16), hidden(17..48), labels(49..52)]

__global__ __launch_bounds__(256) void update_dense3_kernel(
        const float* __restrict__ g_update, const float* __restrict__ g_cell,
        float* __restrict__ hidden,
        const float* __restrict__ x_t, const float* __restrict__ mask,
        const float* __restrict__ labels,
        const float* __restrict__ W1, const float* __restrict__ b1,
        const float* __restrict__ Wl3, const float* __restrict__ bl3,
        const float* __restrict__ Wr3, const float* __restrict__ br3,
        unsigned short* __restrict__ xlh, float* __restrict__ xr) {
    __shared__ float Wl_s[WD];
    __shared__ float Wr_s[WD];
    __shared__ float W1_s[FEAT * HID];
    __shared__ float inp_s[8][DIN];
    __shared__ float hs[8][HID + 1];
    for (int idx = threadIdx.x; idx < WD; idx += 256) {
        Wl_s[idx] = Wl3[idx];
        Wr_s[idx] = Wr3[idx];
    }
    for (int idx = threadIdx.x; idx < FEAT * HID; idx += 256) W1_s[idx] = W1[idx];
    int ni = threadIdx.x >> 5, k = threadIdx.x & 31;
    int node = blockIdx.x * 8 + ni;
    float u = g_update[node * 32 + k];
    float c = g_cell[node * 32 + k];
    float h = hidden[node * 32 + k];
    float hn = u * h + (1.0f - u) * c;
    hidden[node * 32 + k] = hn;
    hs[ni][k] = hn;
    inp_s[ni][17 + k] = hn;
    if (k == 0) inp_s[ni][16] = mask[node];
    if (k < 4)  inp_s[ni][49 + k] = labels[node * 4 + k];
    __syncthreads();
    if (k < 16) {
        float a = b1[k];
        const float* w = &W1_s[k * 32];
#pragma unroll
        for (int i = 0; i < 32; ++i) a += hs[ni][i] * w[i];
        float mv = mask[node];
        inp_s[ni][k] = (mv > 0.5f) ? x_t[node * 16 + k] : a;
    }
    __syncthreads();
    float al = bl3[k], ar = br3[k];
    const float* wl = &Wl_s[k * DIN];
    const float* wr = &Wr_s[k * DIN];
#pragma unroll
    for (int i = 0; i < DIN; ++i) {
        float xv = inp_s[ni][i];
        al += xv * wl[i];
        ar += xv * wr[i];
    }
    xlh[node * 32 + k] = f2bf(al);
    xr[node * 32 + k] = ar;
}

// ---------------- launch ----------------

extern "C" void kernel_launch(void* const* d_in, const int* in_sizes, int n_in,
                              void* d_out, int out_size, void* d_ws, size_t ws_size,
                              hipStream_t stream) {
    const float* x      = (const float*)d_in[0];
    const float* mask   = (const float*)d_in[1];
    const float* labels = (const float*)d_in[2];
    const int*   src    = (const int*)d_in[3];
    const int*   dst    = src + EE;
    // d_in[4] = edge_weight: unused by the reference
    const float* Wl    = (const float*)d_in[5];
    const float* bl    = (const float*)d_in[6];
    const float* Wr    = (const float*)d_in[7];
    const float* br    = (const float*)d_in[8];
    const float* att   = (const float*)d_in[9];
    const float* bconv = (const float*)d_in[10];
    const float* W1    = (const float*)d_in[11];
    const float* b1    = (const float*)d_in[12];
    const float* W2    = (const float*)d_in[13];
    const float* b2    = (const float*)d_in[14];
    float* out = (float*)d_out;

    char* ws = (char*)d_ws;
    size_t off = 0;
    auto alloc = [&](size_t bytes) -> void* {
        void* p = ws + off;
        off = (off + bytes + 255) & ~(size_t)255;
        return p;
    };
    int*   row_ptr = (int*)alloc((NN + 1) * sizeof(int));
    int*   deg     = (int*)alloc(NN * sizeof(int));
    int*   csr_src = (int*)alloc(EE * sizeof(int));
    float* hidden  = (float*)alloc(NN * HID * sizeof(float));
    float* x2      = (float*)alloc(NN * FEAT * sizeof(float));
    unsigned short* xl01h = (unsigned short*)alloc(NN * 64 * sizeof(unsigned short));
    float* xr01    = (float*)alloc(NN * 64 * sizeof(float));
    unsigned short* xlh = (unsigned short*)alloc(NN * 32 * sizeof(unsigned short));
    float* xr      = (float*)alloc(NN * HID * sizeof(float));
    float* g0      = (float*)alloc(NN * HID * sizeof(float));  // reset
    float* g1      = (float*)alloc(NN * HID * sizeof(float));  // update
    float* g2      = (float*)alloc(NN * HID * sizeof(float));  // cell

    // CSR build (dst is identical for every conv, build once per call);
    // segment sort canonicalizes csr_src -> bit-deterministic across calls.
    zero_i32<<<(NN + 255) / 256, 256, 0, stream>>>(deg, NN);
    hist_kernel<<<EE / 256, 256, 0, stream>>>(dst, deg);
    scan_kernel<<<1, 1024, 0, stream>>>(deg, row_ptr);
    zero_i32<<<(NN + 255) / 256, 256, 0, stream>>>(deg, NN);
    scatter_kernel<<<EE / 256, 256, 0, stream>>>(src, dst, row_ptr, deg, csr_src);
    sort_kernel<<<(NN + 255) / 256, 256, 0, stream>>>(row_ptr, csr_src);
    init_kernel<<<NN * HID / 256, 256, 0, stream>>>(x, mask, hidden, x2);

    for (int t = 0; t < TT; ++t) {
        const float* xt = x + (size_t)t * NN * FEAT;
        float* out_t = out + (size_t)t * NN * FEAT;
        // gates 0+1 dense (shared input), bf16 xl + f32 xr
        dense01_kernel<<<NN / 8, 256, 0, stream>>>(x2, mask, labels, hidden,
            Wl, bl, Wr, br, xl01h, xr01);
        // gates 0+1 conv in one CSR walk -> reset (g0), update (g1)
        conv01_kernel<<<NN / 4, 256, 0, stream>>>(row_ptr, csr_src, xl01h, xr01,
            att, bconv, g0, g1);
        // gate 2 dense: cin's h-part = reset*hidden
        dense_kernel<<<NN / 8, 256, 0, stream>>>(x2, mask, labels, hidden, g0,
            Wl + 2 * WD, bl + 2 * HID, Wr + 2 * WD, br + 2 * HID, xlh, xr);
        conv2_kernel<<<NN / 4, 256, 0, stream>>>(row_ptr, csr_src, xlh, xr,
            att + 2 * HID, bconv + 2 * HID, g2);
        // hidden = u*h+(1-u)*c; y1; x1; dense for gate 3 (node-local, fused)
        update_dense3_kernel<<<NN / 8, 256, 0, stream>>>(g1, g2, hidden, xt, mask, labels,
            W1, b1, Wl + 3 * WD, bl + 3 * HID, Wr + 3 * WD, br + 3 * HID, xlh, xr);
        // gate 3 conv + y2/x2/out fused (s never materialized)
        conv3_out_kernel<<<NN / 4, 256, 0, stream>>>(row_ptr, csr_src, xlh, xr,
            att + 3 * HID, bconv + 3 * HID, hidden, W2, b2, xt, mask, x2, out_t);
    }
}

// Round 9
// 1925.553 us; speedup vs baseline: 1.1302x; 1.1302x over previous
//
#include <hip/hip_runtime.h>
#include <math.h>

#define NN   40000
#define EE   640000
#define HID  32
#define FEAT 16
#define LAB  4
#define TT   8
#define DIN  53   // FEAT + LAB + HID + 1
#define WD   (HID * DIN)

// ---------------- bf16 helpers (storage-only; math stays f32) --------------

__device__ __forceinline__ unsigned short f2bf(float f) {
    unsigned int u = __float_as_uint(f);
    unsigned int r = u + 0x7fffu + ((u >> 16) & 1u);   // RNE
    return (unsigned short)(r >> 16);
}
__device__ __forceinline__ float bflo(unsigned int u) { return __uint_as_float(u << 16); }
__device__ __forceinline__ float bfhi(unsigned int u) { return __uint_as_float(u & 0xffff0000u); }
__device__ __forceinline__ void unpack8(uint4 u, float* v) {
    v[0] = bflo(u.x); v[1] = bfhi(u.x);
    v[2] = bflo(u.y); v[3] = bfhi(u.y);
    v[4] = bflo(u.z); v[5] = bfhi(u.z);
    v[6] = bflo(u.w); v[7] = bfhi(u.w);
}

// ---------------- CSR build ----------------

__global__ __launch_bounds__(256) void zero_i32(int* __restrict__ p, int n) {
    int i = blockIdx.x * 256 + threadIdx.x;
    if (i < n) p[i] = 0;
}

__global__ __launch_bounds__(256) void hist_kernel(const int* __restrict__ dst,
                                                   int* __restrict__ deg) {
    int e = blockIdx.x * 256 + threadIdx.x;
    if (e < EE) atomicAdd(&deg[dst[e]], 1);
}

__global__ __launch_bounds__(1024) void scan_kernel(const int* __restrict__ deg,
                                                    int* __restrict__ row_ptr) {
    __shared__ int wsum[16];
    __shared__ int chunk_total;
    int tid = threadIdx.x;
    int lane = tid & 63, wv = tid >> 6;
    int carry = 0;
    if (tid == 0) row_ptr[0] = 0;
    for (int base = 0; base < NN; base += 1024) {
        int i = base + tid;
        int v = (i < NN) ? deg[i] : 0;
        #pragma unroll
        for (int o = 1; o < 64; o <<= 1) {
            int t = __shfl_up(v, o);
            if (lane >= o) v += t;
        }
        if (lane == 63) wsum[wv] = v;
        __syncthreads();
        if (tid < 16) {
            int s = wsum[tid];
            #pragma unroll
            for (int o = 1; o < 16; o <<= 1) {
                int t = __shfl_up(s, o);
                if (tid >= o) s += t;
            }
            wsum[tid] = s;
            if (tid == 15) chunk_total = s;
        }
        __syncthreads();
        int woff = (wv == 0) ? 0 : wsum[wv - 1];
        if (i < NN) row_ptr[i + 1] = carry + woff + v;
        carry += chunk_total;
        __syncthreads();
    }
}

__global__ __launch_bounds__(256) void scatter_kernel(const int* __restrict__ src,
                                                      const int* __restrict__ dst,
                                                      const int* __restrict__ row_ptr,
                                                      int* __restrict__ cursor,
                                                      int* __restrict__ csr_src) {
    int e = blockIdx.x * 256 + threadIdx.x;
    if (e < EE) {
        int d = dst[e];
        int pos = atomicAdd(&cursor[d], 1);
        csr_src[row_ptr[d] + pos] = src[e];
    }
}

// canonicalize: sort each node's segment ascending -> csr_src is a pure
// function of the inputs (atomicAdd ordering unobservable) -> every call
// is bit-identical (graph-replay same-work invariant).
__global__ __launch_bounds__(256) void sort_kernel(const int* __restrict__ row_ptr,
                                                   int* __restrict__ csr_src) {
    int n = blockIdx.x * 256 + threadIdx.x;
    if (n < NN) {
        int beg = row_ptr[n], end = row_ptr[n + 1];
        for (int i = beg + 1; i < end; ++i) {
            int key = csr_src[i];
            int j = i - 1;
            while (j >= beg && csr_src[j] > key) {
                csr_src[j + 1] = csr_src[j];
                --j;
            }
            csr_src[j + 1] = key;
        }
    }
}

// ---------------- state init ----------------

__global__ __launch_bounds__(256) void init_kernel(const float* __restrict__ x0,
                                                   const float* __restrict__ mask,
                                                   float* __restrict__ hidden,
                                                   float* __restrict__ x2) {
    int i = blockIdx.x * 256 + threadIdx.x;
    if (i < NN * HID) hidden[i] = 1.0f;
    if (i < NN * FEAT) {
        int node = i >> 4;
        x2[i] = (mask[node] > 0.5f) ? x0[i] : 0.0f;
    }
}

// ---------------- dense01: both sigmoid-gate projections, 32 nodes/block ---
// inp = [feat16, mask, labels4, h32]; xl packed bf16 [node][gate][32]

__global__ __launch_bounds__(256) void dense01_kernel(const float* __restrict__ feat,
                                                      const float* __restrict__ mask,
                                                      const float* __restrict__ labels,
                                                      const float* __restrict__ hsrc,
                                                      const float* __restrict__ Wl,
                                                      const float* __restrict__ bl,
                                                      const float* __restrict__ Wr,
                                                      const float* __restrict__ br,
                                                      unsigned short* __restrict__ xl01h,
                                                      float* __restrict__ xr01) {
    __shared__ float W_s[4 * WD];     // Wl0 | Wl1 | Wr0 | Wr1
    __shared__ float inp_s[8][DIN];
    for (int idx = threadIdx.x; idx < WD; idx += 256) {
        W_s[idx]          = Wl[idx];
        W_s[WD + idx]     = Wl[WD + idx];
        W_s[2 * WD + idx] = Wr[idx];
        W_s[3 * WD + idx] = Wr[WD + idx];
    }
    int ni = threadIdx.x >> 5, k = threadIdx.x & 31;
    const float* w0 = &W_s[k * DIN];
    const float* w1 = &W_s[WD + k * DIN];
    const float* w2 = &W_s[2 * WD + k * DIN];
    const float* w3 = &W_s[3 * WD + k * DIN];
    float bl0 = bl[k], bl1 = bl[HID + k], br0 = br[k], br1 = br[HID + k];
#pragma unroll
    for (int it = 0; it < 4; ++it) {
        int node = blockIdx.x * 32 + it * 8 + ni;
        __syncthreads();
        for (int i = k; i < DIN; i += 32) {
            float v;
            if (i < 16)       v = feat[node * 16 + i];
            else if (i == 16) v = mask[node];
            else if (i < 21)  v = labels[node * 4 + (i - 17)];
            else              v = hsrc[node * 32 + (i - 21)];
            inp_s[ni][i] = v;
        }
        __syncthreads();
        float l0 = bl0, l1 = bl1, r0 = br0, r1 = br1;
#pragma unroll
        for (int i = 0; i < DIN; ++i) {
            float xv = inp_s[ni][i];
            l0 += xv * w0[i];
            l1 += xv * w1[i];
            r0 += xv * w2[i];
            r1 += xv * w3[i];
        }
        xl01h[node * 64 + k]      = f2bf(l0);
        xl01h[node * 64 + 32 + k] = f2bf(l1);
        xr01[node * 64 + k]      = r0;
        xr01[node * 64 + 32 + k] = r1;
    }
}

// ---------------- dense (cell gate), 32 nodes/block ------------------------
// inp = [feat16, mask, labels4, h32 * hmul]; xl packed bf16

__global__ __launch_bounds__(256) void dense_kernel(const float* __restrict__ feat,
                                                    const float* __restrict__ mask,
                                                    const float* __restrict__ labels,
                                                    const float* __restrict__ hsrc,
                                                    const float* __restrict__ hmul,
                                                    const float* __restrict__ Wl,
                                                    const float* __restrict__ bl,
                                                    const float* __restrict__ Wr,
                                                    const float* __restrict__ br,
                                                    unsigned short* __restrict__ xlh,
                                                    float* __restrict__ xr) {
    __shared__ float Wl_s[WD];
    __shared__ float Wr_s[WD];
    __shared__ float inp_s[8][DIN];
    for (int idx = threadIdx.x; idx < WD; idx += 256) {
        Wl_s[idx] = Wl[idx];
        Wr_s[idx] = Wr[idx];
    }
    int ni = threadIdx.x >> 5, k = threadIdx.x & 31;
    const float* wlr = &Wl_s[k * DIN];
    const float* wrr = &Wr_s[k * DIN];
    float blv = bl[k], brv = br[k];
#pragma unroll
    for (int it = 0; it < 4; ++it) {
        int node = blockIdx.x * 32 + it * 8 + ni;
        __syncthreads();
        for (int i = k; i < DIN; i += 32) {
            float v;
            if (i < 16)       v = feat[node * 16 + i];
            else if (i == 16) v = mask[node];
            else if (i < 21)  v = labels[node * 4 + (i - 17)];
            else              v = hsrc[node * 32 + (i - 21)] * hmul[node * 32 + (i - 21)];
            inp_s[ni][i] = v;
        }
        __syncthreads();
        float al = blv, ar = brv;
#pragma unroll
        for (int i = 0; i < DIN; ++i) {
            float xv = inp_s[ni][i];
            al += xv * wlr[i];
            ar += xv * wrr[i];
        }
        xlh[node * 32 + k] = f2bf(al);
        xr[node * 32 + k] = ar;
    }
}

// -------- conv helpers ------------------------------------------------------

__device__ __forceinline__ float edge_score8(const float* v, const float* xr, const float* at) {
    float part = 0.0f;
#pragma unroll
    for (int i = 0; i < 8; ++i) {
        float z = v[i] + xr[i];
        z = (z > 0.0f) ? z : 0.2f * z;
        part += z * at[i];
    }
    part += __shfl_xor(part, 1);
    part += __shfl_xor(part, 2);
    return part;
}

__device__ __forceinline__ void online_update8(float e, float& m, float& den, float* acc,
                                               const float* v) {
    if (e > m) {
        float sc = __expf(m - e);
        den *= sc;
#pragma unroll
        for (int i = 0; i < 8; ++i) acc[i] *= sc;
        m = e;
    }
    float a = __expf(e - m);
    den += a;
#pragma unroll
    for (int i = 0; i < 8; ++i) acc[i] += a * v[i];
}

// merge across 16 groups (full wave; masks 4,8,16,32)
__device__ __forceinline__ void merge_full(float m, float den, const float* acc,
                                           bool ne, float* o) {
    if (ne) {
        float mt = m;
        mt = fmaxf(mt, __shfl_xor(mt, 4));
        mt = fmaxf(mt, __shfl_xor(mt, 8));
        mt = fmaxf(mt, __shfl_xor(mt, 16));
        mt = fmaxf(mt, __shfl_xor(mt, 32));
        float sc = __expf(m - mt);
        float d = den * sc;
        d += __shfl_xor(d, 4);
        d += __shfl_xor(d, 8);
        d += __shfl_xor(d, 16);
        d += __shfl_xor(d, 32);
#pragma unroll
        for (int i = 0; i < 8; ++i) {
            float t = acc[i] * sc;
            t += __shfl_xor(t, 4);
            t += __shfl_xor(t, 8);
            t += __shfl_xor(t, 16);
            t += __shfl_xor(t, 32);
            o[i] = t / d;
        }
    } else {
#pragma unroll
        for (int i = 0; i < 8; ++i) o[i] = 0.0f;
    }
}

// merge across 8 groups (32-lane half; masks 4,8,16)
__device__ __forceinline__ void merge_half(float m, float den, const float* acc,
                                           bool ne, float* o) {
    if (ne) {
        float mt = m;
        mt = fmaxf(mt, __shfl_xor(mt, 4));
        mt = fmaxf(mt, __shfl_xor(mt, 8));
        mt = fmaxf(mt, __shfl_xor(mt, 16));
        float sc = __expf(m - mt);
        float d = den * sc;
        d += __shfl_xor(d, 4);
        d += __shfl_xor(d, 8);
        d += __shfl_xor(d, 16);
#pragma unroll
        for (int i = 0; i < 8; ++i) {
            float t = acc[i] * sc;
            t += __shfl_xor(t, 4);
            t += __shfl_xor(t, 8);
            t += __shfl_xor(t, 16);
            o[i] = t / d;
        }
    } else {
#pragma unroll
        for (int i = 0; i < 8; ++i) o[i] = 0.0f;
    }
}

// ---------------- conv01: half-wave per gate (lanes 0-31 g0, 32-63 g1) -----
// 8 groups x 4 lanes per half; bf16 gather.

__global__ __launch_bounds__(256) void conv01_kernel(const int* __restrict__ row_ptr,
                                                     const int* __restrict__ csr_src,
                                                     const unsigned short* __restrict__ xl01h,
                                                     const float* __restrict__ xr01,
                                                     const float* __restrict__ att,
                                                     const float* __restrict__ bconv,
                                                     float* __restrict__ g0,
                                                     float* __restrict__ g1) {
    int wid  = threadIdx.x >> 6;
    int lane = threadIdx.x & 63;
    int h  = lane >> 5;          // gate
    int hl = lane & 31;
    int g = hl >> 2, j = hl & 3;
    int n = blockIdx.x * 4 + wid;
    int c0 = j * 8;
    int beg = row_ptr[n], end = row_ptr[n + 1];

    float at[8], xr[8];
    {
        float4 a0 = *(const float4*)(att + h * 32 + c0);
        float4 a1 = *(const float4*)(att + h * 32 + c0 + 4);
        at[0] = a0.x; at[1] = a0.y; at[2] = a0.z; at[3] = a0.w;
        at[4] = a1.x; at[5] = a1.y; at[6] = a1.z; at[7] = a1.w;
        float4 r0 = *(const float4*)(xr01 + n * 64 + h * 32 + c0);
        float4 r1 = *(const float4*)(xr01 + n * 64 + h * 32 + c0 + 4);
        xr[0] = r0.x; xr[1] = r0.y; xr[2] = r0.z; xr[3] = r0.w;
        xr[4] = r1.x; xr[5] = r1.y; xr[6] = r1.z; xr[7] = r1.w;
    }

    float m = -INFINITY, den = 0.0f, acc[8] = {0, 0, 0, 0, 0, 0, 0, 0};
    for (int p = beg + g; p < end; p += 8) {
        int s = csr_src[p];
        uint4 u = *(const uint4*)(xl01h + (size_t)s * 64 + h * 32 + c0);
        float v[8];
        unpack8(u, v);
        float e = edge_score8(v, xr, at);
        online_update8(e, m, den, acc, v);
    }
    float o[8];
    merge_half(m, den, acc, beg < end, o);

    if (hl < 4) {
        const float* bc = bconv + h * 32 + c0;
        float r[8];
#pragma unroll
        for (int i = 0; i < 8; ++i) r[i] = 1.0f / (1.0f + __expf(-(o[i] + bc[i])));
        float* outp = (h ? g1 : g0) + n * 32 + c0;
        ((float4*)outp)[0] = make_float4(r[0], r[1], r[2], r[3]);
        ((float4*)outp)[1] = make_float4(r[4], r[5], r[6], r[7]);
    }
}

// ---------------- conv2 (cell gate, tanh): full wave, bf16 gather ----------

__global__ __launch_bounds__(256) void conv2_kernel(const int* __restrict__ row_ptr,
                                                    const int* __restrict__ csr_src,
                                                    const unsigned short* __restrict__ xlh,
                                                    const float* __restrict__ xr,
                                                    const float* __restrict__ att,
                                                    const float* __restrict__ bconv,
                                                    float* __restrict__ out) {
    int wid  = threadIdx.x >> 6;
    int lane = threadIdx.x & 63;
    int g = lane >> 2, j = lane & 3;
    int n = blockIdx.x * 4 + wid;
    int c0 = j * 8;
    int beg = row_ptr[n], end = row_ptr[n + 1];

    float at[8], xrv[8];
    {
        float4 a0 = *(const float4*)(att + c0);
        float4 a1 = *(const float4*)(att + c0 + 4);
        at[0] = a0.x; at[1] = a0.y; at[2] = a0.z; at[3] = a0.w;
        at[4] = a1.x; at[5] = a1.y; at[6] = a1.z; at[7] = a1.w;
        float4 r0 = *(const float4*)(xr + n * 32 + c0);
        float4 r1 = *(const float4*)(xr + n * 32 + c0 + 4);
        xrv[0] = r0.x; xrv[1] = r0.y; xrv[2] = r0.z; xrv[3] = r0.w;
        xrv[4] = r1.x; xrv[5] = r1.y; xrv[6] = r1.z; xrv[7] = r1.w;
    }

    float m = -INFINITY, den = 0.0f, acc[8] = {0, 0, 0, 0, 0, 0, 0, 0};
    for (int p = beg + g; p < end; p += 16) {
        int s = csr_src[p];
        uint4 u = *(const uint4*)(xlh + (size_t)s * 32 + c0);
        float v[8];
        unpack8(u, v);
        float e = edge_score8(v, xrv, at);
        online_update8(e, m, den, acc, v);
    }
    float o[8];
    merge_full(m, den, acc, beg < end, o);

    if (g == 0) {
        const float* bc = bconv + c0;
        float r[8];
#pragma unroll
        for (int i = 0; i < 8; ++i) r[i] = tanhf(o[i] + bc[i]);
        float* op = out + n * 32 + c0;
        ((float4*)op)[0] = make_float4(r[0], r[1], r[2], r[3]);
        ((float4*)op)[1] = make_float4(r[4], r[5], r[6], r[7]);
    }
}

// ---------------- conv3 + y2/x2/out fused, bf16 gather ---------------------

__global__ __launch_bounds__(256) void conv3_out_kernel(const int* __restrict__ row_ptr,
                                                        const int* __restrict__ csr_src,
                                                        const unsigned short* __restrict__ xlh,
                                                        const float* __restrict__ xr,
                                                        const float* __restrict__ att,
                                                        const float* __restrict__ bconv,
                                                        const float* __restrict__ hidden,
                                                        const float* __restrict__ W2,
                                                        const float* __restrict__ b2,
                                                        const float* __restrict__ x_t,
                                                        const float* __restrict__ mask,
                                                        float* __restrict__ x2,
                                                        float* __restrict__ out_t) {
    __shared__ float W2s[64 * 16];   // transposed [c][f]
    for (int idx = threadIdx.x; idx < 64 * 16; idx += 256) {
        int f = idx & 15, c = idx >> 4;
        W2s[c * 16 + f] = W2[f * 64 + c];
    }
    __syncthreads();

    int wid  = threadIdx.x >> 6;
    int lane = threadIdx.x & 63;
    int g = lane >> 2, j = lane & 3;
    int n = blockIdx.x * 4 + wid;
    int c0 = j * 8;
    int beg = row_ptr[n], end = row_ptr[n + 1];

    float at[8], xrv[8];
    {
        float4 a0 = *(const float4*)(att + c0);
        float4 a1 = *(const float4*)(att + c0 + 4);
        at[0] = a0.x; at[1] = a0.y; at[2] = a0.z; at[3] = a0.w;
        at[4] = a1.x; at[5] = a1.y; at[6] = a1.z; at[7] = a1.w;
        float4 r0 = *(const float4*)(xr + n * 32 + c0);
        float4 r1 = *(const float4*)(xr + n * 32 + c0 + 4);
        xrv[0] = r0.x; xrv[1] = r0.y; xrv[2] = r0.z; xrv[3] = r0.w;
        xrv[4] = r1.x; xrv[5] = r1.y; xrv[6] = r1.z; xrv[7] = r1.w;
    }

    float m = -INFINITY, den = 0.0f, acc[8] = {0, 0, 0, 0, 0, 0, 0, 0};
    for (int p = beg + g; p < end; p += 16) {
        int s = csr_src[p];
        uint4 u = *(const uint4*)(xlh + (size_t)s * 32 + c0);
        float v[8];
        unpack8(u, v);
        float e = edge_score8(v, xrv, at);
        online_update8(e, m, den, acc, v);
    }
    float o[8];
    merge_full(m, den, acc, beg < end, o);

    // s (relu), j-sliced, in all lanes
    float r[8], hv[8];
    {
        const float* bc = bconv + c0;
#pragma unroll
        for (int i = 0; i < 8; ++i) r[i] = fmaxf(o[i] + bc[i], 0.0f);
        float4 h0 = *(const float4*)(hidden + n * 32 + c0);
        float4 h1 = *(const float4*)(hidden + n * 32 + c0 + 4);
        hv[0] = h0.x; hv[1] = h0.y; hv[2] = h0.z; hv[3] = h0.w;
        hv[4] = h1.x; hv[5] = h1.y; hv[6] = h1.z; hv[7] = h1.w;
    }

    int f = lane & 15;
    int base = lane & ~3;
    float y = b2[f];
#pragma unroll
    for (int j2 = 0; j2 < 4; ++j2) {
#pragma unroll
        for (int i = 0; i < 8; ++i) {
            float sv = __shfl(r[i], base + j2);
            float hh = __shfl(hv[i], base + j2);
            int c = j2 * 8 + i;
            y += sv * W2s[c * 16 + f] + hh * W2s[(32 + c) * 16 + f];
        }
    }
    if (lane < 16) {
        float mv = mask[n];
        float xv = x_t[n * 16 + f];
        float rr = (mv > 0.5f) ? xv : y;
        x2[n * 16 + f] = rr;
        out_t[n * 16 + f] = rr;
    }
}

// ---------------- hidden update + y1/x1 + dense3, 32 nodes/block -----------
// ft2 = [x1(0..15), mask(16), hidden(17..48), labels(49..52)]

__global__ __launch_bounds__(256) void update_dense3_kernel(
        const float* __restrict__ g_update, const float* __restrict__ g_cell,
        float* __restrict__ hidden,
        const float* __restrict__ x_t, const float* __restrict__ mask,
        const float* __restrict__ labels,
        const float* __restrict__ W1, const float* __restrict__ b1,
        const float* __restrict__ Wl3, const float* __restrict__ bl3,
        const float* __restrict__ Wr3, const float* __restrict__ br3,
        unsigned short* __restrict__ xlh, float* __restrict__ xr) {
    __shared__ float Wl_s[WD];
    __shared__ float Wr_s[WD];
    __shared__ float W1_s[FEAT * HID];
    __shared__ float inp_s[8][DIN];
    __shared__ float hs[8][HID + 1];
    for (int idx = threadIdx.x; idx < WD; idx += 256) {
        Wl_s[idx] = Wl3[idx];
        Wr_s[idx] = Wr3[idx];
    }
    for (int idx = threadIdx.x; idx < FEAT * HID; idx += 256) W1_s[idx] = W1[idx];
    int ni = threadIdx.x >> 5, k = threadIdx.x & 31;
    const float* wl = &Wl_s[k * DIN];
    const float* wr = &Wr_s[k * DIN];
    float bl3v = bl3[k], br3v = br3[k];
#pragma unroll
    for (int it = 0; it < 4; ++it) {
        int node = blockIdx.x * 32 + it * 8 + ni;
        __syncthreads();
        float u = g_update[node * 32 + k];
        float c = g_cell[node * 32 + k];
        float h = hidden[node * 32 + k];
        float hn = u * h + (1.0f - u) * c;
        hidden[node * 32 + k] = hn;
        hs[ni][k] = hn;
        inp_s[ni][17 + k] = hn;
        if (k == 0) inp_s[ni][16] = mask[node];
        if (k < 4)  inp_s[ni][49 + k] = labels[node * 4 + k];
        __syncthreads();
        if (k < 16) {
            float a = b1[k];
            const float* w = &W1_s[k * 32];
#pragma unroll
            for (int i = 0; i < 32; ++i) a += hs[ni][i] * w[i];
            float mv = mask[node];
            inp_s[ni][k] = (mv > 0.5f) ? x_t[node * 16 + k] : a;
        }
        __syncthreads();
        float al = bl3v, ar = br3v;
#pragma unroll
        for (int i = 0; i < DIN; ++i) {
            float xv = inp_s[ni][i];
            al += xv * wl[i];
            ar += xv * wr[i];
        }
        xlh[node * 32 + k] = f2bf(al);
        xr[node * 32 + k] = ar;
    }
}

// ---------------- launch ----------------

extern "C" void kernel_launch(void* const* d_in, const int* in_sizes, int n_in,
                              void* d_out, int out_size, void* d_ws, size_t ws_size,
                              hipStream_t stream) {
    const float* x      = (const float*)d_in[0];
    const float* mask   = (const float*)d_in[1];
    const float* labels = (const float*)d_in[2];
    const int*   src    = (const int*)d_in[3];
    const int*   dst    = src + EE;
    // d_in[4] = edge_weight: unused by the reference
    const float* Wl    = (const float*)d_in[5];
    const float* bl    = (const float*)d_in[6];
    const float* Wr    = (const float*)d_in[7];
    const float* br    = (const float*)d_in[8];
    const float* att   = (const float*)d_in[9];
    const float* bconv = (const float*)d_in[10];
    const float* W1    = (const float*)d_in[11];
    const float* b1    = (const float*)d_in[12];
    const float* W2    = (const float*)d_in[13];
    const float* b2    = (const float*)d_in[14];
    float* out = (float*)d_out;

    char* ws = (char*)d_ws;
    size_t off = 0;
    auto alloc = [&](size_t bytes) -> void* {
        void* p = ws + off;
        off = (off + bytes + 255) & ~(size_t)255;
        return p;
    };
    int*   row_ptr = (int*)alloc((NN + 1) * sizeof(int));
    int*   deg     = (int*)alloc(NN * sizeof(int));
    int*   csr_src = (int*)alloc(EE * sizeof(int));
    float* hidden  = (float*)alloc(NN * HID * sizeof(float));
    float* x2      = (float*)alloc(NN * FEAT * sizeof(float));
    unsigned short* xl01h = (unsigned short*)alloc(NN * 64 * sizeof(unsigned short));
    float* xr01    = (float*)alloc(NN * 64 * sizeof(float));
    unsigned short* xlh = (unsigned short*)alloc(NN * 32 * sizeof(unsigned short));
    float* xr      = (float*)alloc(NN * HID * sizeof(float));
    float* g0      = (float*)alloc(NN * HID * sizeof(float));  // reset
    float* g1      = (float*)alloc(NN * HID * sizeof(float));  // update
    float* g2      = (float*)alloc(NN * HID * sizeof(float));  // cell

    // CSR build (dst is identical for every conv, build once per call);
    // segment sort canonicalizes csr_src -> bit-deterministic across calls.
    zero_i32<<<(NN + 255) / 256, 256, 0, stream>>>(deg, NN);
    hist_kernel<<<EE / 256, 256, 0, stream>>>(dst, deg);
    scan_kernel<<<1, 1024, 0, stream>>>(deg, row_ptr);
    zero_i32<<<(NN + 255) / 256, 256, 0, stream>>>(deg, NN);
    scatter_kernel<<<EE / 256, 256, 0, stream>>>(src, dst, row_ptr, deg, csr_src);
    sort_kernel<<<(NN + 255) / 256, 256, 0, stream>>>(row_ptr, csr_src);
    init_kernel<<<NN * HID / 256, 256, 0, stream>>>(x, mask, hidden, x2);

    for (int t = 0; t < TT; ++t) {
        const float* xt = x + (size_t)t * NN * FEAT;
        float* out_t = out + (size_t)t * NN * FEAT;
        // gates 0+1 dense (shared input), bf16 xl + f32 xr
        dense01_kernel<<<NN / 32, 256, 0, stream>>>(x2, mask, labels, hidden,
            Wl, bl, Wr, br, xl01h, xr01);
        // gates 0+1 conv, half-wave per gate -> reset (g0), update (g1)
        conv01_kernel<<<NN / 4, 256, 0, stream>>>(row_ptr, csr_src, xl01h, xr01,
            att, bconv, g0, g1);
        // gate 2 dense: cin's h-part = reset*hidden
        dense_kernel<<<NN / 32, 256, 0, stream>>>(x2, mask, labels, hidden, g0,
            Wl + 2 * WD, bl + 2 * HID, Wr + 2 * WD, br + 2 * HID, xlh, xr);
        conv2_kernel<<<NN / 4, 256, 0, stream>>>(row_ptr, csr_src, xlh, xr,
            att + 2 * HID, bconv + 2 * HID, g2);
        // hidden = u*h+(1-u)*c; y1; x1; dense for gate 3 (node-local, fused)
        update_dense3_kernel<<<NN / 32, 256, 0, stream>>>(g1, g2, hidden, xt, mask, labels,
            W1, b1, Wl + 3 * WD, bl + 3 * HID, Wr + 3 * WD, br + 3 * HID, xlh, xr);
        // gate 3 conv + y2/x2/out fused (s never materialized)
        conv3_out_kernel<<<NN / 4, 256, 0, stream>>>(row_ptr, csr_src, xlh, xr,
            att + 3 * HID, bconv + 3 * HID, hidden, W2, b2, xt, mask, x2, out_t);
    }
}

// Round 10
// 1904.202 us; speedup vs baseline: 1.1428x; 1.0112x over previous
//
#include <hip/hip_runtime.h>
#include <math.h>

#define NN   40000
#define EE   640000
#define HID  32
#define FEAT 16
#define LAB  4
#define TT   8
#define DIN  53   // FEAT + LAB + HID + 1
#define WD   (HID * DIN)

// ---------------- bf16 helpers (storage-only; math stays f32) --------------

__device__ __forceinline__ unsigned short f2bf(float f) {
    unsigned int u = __float_as_uint(f);
    unsigned int r = u + 0x7fffu + ((u >> 16) & 1u);   // RNE
    return (unsigned short)(r >> 16);
}
__device__ __forceinline__ float bflo(unsigned int u) { return __uint_as_float(u << 16); }
__device__ __forceinline__ float bfhi(unsigned int u) { return __uint_as_float(u & 0xffff0000u); }
__device__ __forceinline__ void unpack8(uint4 u, float* v) {
    v[0] = bflo(u.x); v[1] = bfhi(u.x);
    v[2] = bflo(u.y); v[3] = bfhi(u.y);
    v[4] = bflo(u.z); v[5] = bfhi(u.z);
    v[6] = bflo(u.w); v[7] = bfhi(u.w);
}

// ---------------- CSR build ----------------

__global__ __launch_bounds__(256) void zero_i32(int* __restrict__ p, int n) {
    int i = blockIdx.x * 256 + threadIdx.x;
    if (i < n) p[i] = 0;
}

__global__ __launch_bounds__(256) void hist_kernel(const int* __restrict__ dst,
                                                   int* __restrict__ deg) {
    int e = blockIdx.x * 256 + threadIdx.x;
    if (e < EE) atomicAdd(&deg[dst[e]], 1);
}

__global__ __launch_bounds__(1024) void scan_kernel(const int* __restrict__ deg,
                                                    int* __restrict__ row_ptr) {
    __shared__ int wsum[16];
    __shared__ int chunk_total;
    int tid = threadIdx.x;
    int lane = tid & 63, wv = tid >> 6;
    int carry = 0;
    if (tid == 0) row_ptr[0] = 0;
    for (int base = 0; base < NN; base += 1024) {
        int i = base + tid;
        int v = (i < NN) ? deg[i] : 0;
        #pragma unroll
        for (int o = 1; o < 64; o <<= 1) {
            int t = __shfl_up(v, o);
            if (lane >= o) v += t;
        }
        if (lane == 63) wsum[wv] = v;
        __syncthreads();
        if (tid < 16) {
            int s = wsum[tid];
            #pragma unroll
            for (int o = 1; o < 16; o <<= 1) {
                int t = __shfl_up(s, o);
                if (tid >= o) s += t;
            }
            wsum[tid] = s;
            if (tid == 15) chunk_total = s;
        }
        __syncthreads();
        int woff = (wv == 0) ? 0 : wsum[wv - 1];
        if (i < NN) row_ptr[i + 1] = carry + woff + v;
        carry += chunk_total;
        __syncthreads();
    }
}

__global__ __launch_bounds__(256) void scatter_kernel(const int* __restrict__ src,
                                                      const int* __restrict__ dst,
                                                      const int* __restrict__ row_ptr,
                                                      int* __restrict__ cursor,
                                                      int* __restrict__ csr_src) {
    int e = blockIdx.x * 256 + threadIdx.x;
    if (e < EE) {
        int d = dst[e];
        int pos = atomicAdd(&cursor[d], 1);
        csr_src[row_ptr[d] + pos] = src[e];
    }
}

// canonicalize: sort each node's segment ascending. Wave-per-node bitonic
// network: data-independent (deterministic), swaps-only (permutation), so
// csr_src is a pure function of the inputs -> bit-identical every call.
__global__ __launch_bounds__(256) void sort_kernel(const int* __restrict__ row_ptr,
                                                   int* __restrict__ csr_src) {
    int wid = threadIdx.x >> 6, lane = threadIdx.x & 63;
    int n = blockIdx.x * 4 + wid;
    if (n >= NN) return;
    int beg = row_ptr[n], end = row_ptr[n + 1];
    int deg = end - beg;
    if (deg <= 1) return;
    if (deg <= 64) {
        int v = (lane < deg) ? csr_src[beg + lane] : 0x7fffffff;
        #pragma unroll
        for (int k = 2; k <= 64; k <<= 1) {
            #pragma unroll
            for (int jj = k >> 1; jj >= 1; jj >>= 1) {
                int pv = __shfl_xor(v, jj);
                bool up = ((lane & k) == 0);
                bool lower = ((lane & jj) == 0);
                int mn = min(v, pv), mx = max(v, pv);
                v = (lower == up) ? mn : mx;
            }
        }
        if (lane < deg) csr_src[beg + lane] = v;
    } else if (lane == 0) {   // Poisson(16) tail never reaches 64; safe fallback
        for (int i = beg + 1; i < end; ++i) {
            int key = csr_src[i];
            int j = i - 1;
            while (j >= beg && csr_src[j] > key) {
                csr_src[j + 1] = csr_src[j];
                --j;
            }
            csr_src[j + 1] = key;
        }
    }
}

// ---------------- state init ----------------

__global__ __launch_bounds__(256) void init_kernel(const float* __restrict__ x0,
                                                   const float* __restrict__ mask,
                                                   float* __restrict__ hidden,
                                                   float* __restrict__ x2) {
    int i = blockIdx.x * 256 + threadIdx.x;
    if (i < NN * HID) hidden[i] = 1.0f;
    if (i < NN * FEAT) {
        int node = i >> 4;
        x2[i] = (mask[node] > 0.5f) ? x0[i] : 0.0f;
    }
}

// ---------------- dense01: both sigmoid-gate projections, 32 nodes/block ---
// inp = [feat16, mask, labels4, h32]; xl packed bf16 [node][gate][32]

__global__ __launch_bounds__(256) void dense01_kernel(const float* __restrict__ feat,
                                                      const float* __restrict__ mask,
                                                      const float* __restrict__ labels,
                                                      const float* __restrict__ hsrc,
                                                      const float* __restrict__ Wl,
                                                      const float* __restrict__ bl,
                                                      const float* __restrict__ Wr,
                                                      const float* __restrict__ br,
                                                      unsigned short* __restrict__ xl01h,
                                                      float* __restrict__ xr01) {
    __shared__ float W_s[4 * WD];     // Wl0 | Wl1 | Wr0 | Wr1
    __shared__ float inp_s[8][DIN];
    for (int idx = threadIdx.x; idx < WD; idx += 256) {
        W_s[idx]          = Wl[idx];
        W_s[WD + idx]     = Wl[WD + idx];
        W_s[2 * WD + idx] = Wr[idx];
        W_s[3 * WD + idx] = Wr[WD + idx];
    }
    int ni = threadIdx.x >> 5, k = threadIdx.x & 31;
    const float* w0 = &W_s[k * DIN];
    const float* w1 = &W_s[WD + k * DIN];
    const float* w2 = &W_s[2 * WD + k * DIN];
    const float* w3 = &W_s[3 * WD + k * DIN];
    float bl0 = bl[k], bl1 = bl[HID + k], br0 = br[k], br1 = br[HID + k];
#pragma unroll
    for (int it = 0; it < 4; ++it) {
        int node = blockIdx.x * 32 + it * 8 + ni;
        __syncthreads();
        for (int i = k; i < DIN; i += 32) {
            float v;
            if (i < 16)       v = feat[node * 16 + i];
            else if (i == 16) v = mask[node];
            else if (i < 21)  v = labels[node * 4 + (i - 17)];
            else              v = hsrc[node * 32 + (i - 21)];
            inp_s[ni][i] = v;
        }
        __syncthreads();
        float l0 = bl0, l1 = bl1, r0 = br0, r1 = br1;
#pragma unroll
        for (int i = 0; i < DIN; ++i) {
            float xv = inp_s[ni][i];
            l0 += xv * w0[i];
            l1 += xv * w1[i];
            r0 += xv * w2[i];
            r1 += xv * w3[i];
        }
        xl01h[node * 64 + k]      = f2bf(l0);
        xl01h[node * 64 + 32 + k] = f2bf(l1);
        xr01[node * 64 + k]      = r0;
        xr01[node * 64 + 32 + k] = r1;
    }
}

// -------- conv helpers ------------------------------------------------------

__device__ __forceinline__ float edge_score8(const float* v, const float* xr, const float* at) {
    float part = 0.0f;
#pragma unroll
    for (int i = 0; i < 8; ++i) {
        float z = v[i] + xr[i];
        z = (z > 0.0f) ? z : 0.2f * z;
        part += z * at[i];
    }
    part += __shfl_xor(part, 1);
    part += __shfl_xor(part, 2);
    return part;
}

__device__ __forceinline__ void online_update8(float e, float& m, float& den, float* acc,
                                               const float* v) {
    if (e > m) {
        float sc = __expf(m - e);
        den *= sc;
#pragma unroll
        for (int i = 0; i < 8; ++i) acc[i] *= sc;
        m = e;
    }
    float a = __expf(e - m);
    den += a;
#pragma unroll
    for (int i = 0; i < 8; ++i) acc[i] += a * v[i];
}

// merge across 16 groups (full wave; masks 4,8,16,32)
__device__ __forceinline__ void merge_full(float m, float den, const float* acc,
                                           bool ne, float* o) {
    if (ne) {
        float mt = m;
        mt = fmaxf(mt, __shfl_xor(mt, 4));
        mt = fmaxf(mt, __shfl_xor(mt, 8));
        mt = fmaxf(mt, __shfl_xor(mt, 16));
        mt = fmaxf(mt, __shfl_xor(mt, 32));
        float sc = __expf(m - mt);
        float d = den * sc;
        d += __shfl_xor(d, 4);
        d += __shfl_xor(d, 8);
        d += __shfl_xor(d, 16);
        d += __shfl_xor(d, 32);
#pragma unroll
        for (int i = 0; i < 8; ++i) {
            float t = acc[i] * sc;
            t += __shfl_xor(t, 4);
            t += __shfl_xor(t, 8);
            t += __shfl_xor(t, 16);
            t += __shfl_xor(t, 32);
            o[i] = t / d;
        }
    } else {
#pragma unroll
        for (int i = 0; i < 8; ++i) o[i] = 0.0f;
    }
}

// merge across 8 groups (32-lane half; masks 4,8,16)
__device__ __forceinline__ void merge_half(float m, float den, const float* acc,
                                           bool ne, float* o) {
    if (ne) {
        float mt = m;
        mt = fmaxf(mt, __shfl_xor(mt, 4));
        mt = fmaxf(mt, __shfl_xor(mt, 8));
        mt = fmaxf(mt, __shfl_xor(mt, 16));
        float sc = __expf(m - mt);
        float d = den * sc;
        d += __shfl_xor(d, 4);
        d += __shfl_xor(d, 8);
        d += __shfl_xor(d, 16);
#pragma unroll
        for (int i = 0; i < 8; ++i) {
            float t = acc[i] * sc;
            t += __shfl_xor(t, 4);
            t += __shfl_xor(t, 8);
            t += __shfl_xor(t, 16);
            o[i] = t / d;
        }
    } else {
#pragma unroll
        for (int i = 0; i < 8; ++i) o[i] = 0.0f;
    }
}

// ---------------- conv01 + dense2 fused ------------------------------------
// Half-wave per gate (lanes 0-31 reset, 32-63 update), 8 groups x 4 lanes.
// Epilogue: g1 (update) written; reset consumed in-kernel:
// cin = [x2(0..15), mask(16), labels(17..20), reset*hidden(21..52)],
// then xl2 = cin@Wl2.T+bl2 (bf16), xr2 = cin@Wr2.T+br2.

__global__ __launch_bounds__(256) void conv01_d2_kernel(
        const int* __restrict__ row_ptr, const int* __restrict__ csr_src,
        const unsigned short* __restrict__ xl01h, const float* __restrict__ xr01,
        const float* __restrict__ att, const float* __restrict__ bconv,
        const float* __restrict__ x2, const float* __restrict__ mask,
        const float* __restrict__ labels, const float* __restrict__ hidden,
        const float* __restrict__ Wl2, const float* __restrict__ bl2,
        const float* __restrict__ Wr2, const float* __restrict__ br2,
        float* __restrict__ g1,
        unsigned short* __restrict__ xlh, float* __restrict__ xr) {
    __shared__ float Wl_s[WD];
    __shared__ float Wr_s[WD];
    __shared__ float cin_s[4][DIN + 3];
    for (int idx = threadIdx.x; idx < WD; idx += 256) {
        Wl_s[idx] = Wl2[idx];
        Wr_s[idx] = Wr2[idx];
    }
    __syncthreads();

    int wid  = threadIdx.x >> 6;
    int lane = threadIdx.x & 63;
    int h  = lane >> 5;          // gate
    int hl = lane & 31;
    int g = hl >> 2, j = hl & 3;
    int n = blockIdx.x * 4 + wid;
    int c0 = j * 8;
    int beg = row_ptr[n], end = row_ptr[n + 1];

    float at[8], xrv[8];
    {
        float4 a0 = *(const float4*)(att + h * 32 + c0);
        float4 a1 = *(const float4*)(att + h * 32 + c0 + 4);
        at[0] = a0.x; at[1] = a0.y; at[2] = a0.z; at[3] = a0.w;
        at[4] = a1.x; at[5] = a1.y; at[6] = a1.z; at[7] = a1.w;
        float4 r0 = *(const float4*)(xr01 + n * 64 + h * 32 + c0);
        float4 r1 = *(const float4*)(xr01 + n * 64 + h * 32 + c0 + 4);
        xrv[0] = r0.x; xrv[1] = r0.y; xrv[2] = r0.z; xrv[3] = r0.w;
        xrv[4] = r1.x; xrv[5] = r1.y; xrv[6] = r1.z; xrv[7] = r1.w;
    }

    float m = -INFINITY, den = 0.0f, acc[8] = {0, 0, 0, 0, 0, 0, 0, 0};
    for (int p = beg + g; p < end; p += 8) {
        int s = csr_src[p];
        uint4 u = *(const uint4*)(xl01h + (size_t)s * 64 + h * 32 + c0);
        float v[8];
        unpack8(u, v);
        float e = edge_score8(v, xrv, at);
        online_update8(e, m, den, acc, v);
    }
    float o[8];
    merge_half(m, den, acc, beg < end, o);

    // gate value (sigmoid) for this half's j-slice
    const float* bc = bconv + h * 32 + c0;
    float r[8];
#pragma unroll
    for (int i = 0; i < 8; ++i) r[i] = 1.0f / (1.0f + __expf(-(o[i] + bc[i])));

    if (h == 1 && g == 0) {          // update -> g1
        float* p1 = g1 + n * 32 + c0;
        ((float4*)p1)[0] = make_float4(r[0], r[1], r[2], r[3]);
        ((float4*)p1)[1] = make_float4(r[4], r[5], r[6], r[7]);
    }
    if (h == 0 && g == 0) {          // reset*hidden -> cin[21..52]
        float4 h0 = *(const float4*)(hidden + n * 32 + c0);
        float4 h1 = *(const float4*)(hidden + n * 32 + c0 + 4);
        float hv[8] = {h0.x, h0.y, h0.z, h0.w, h1.x, h1.y, h1.z, h1.w};
#pragma unroll
        for (int i = 0; i < 8; ++i) cin_s[wid][21 + c0 + i] = r[i] * hv[i];
    }
    if (h == 1 && hl < 21) {         // feat/mask/labels -> cin[0..20]
        int i = hl;
        float v;
        if (i < 16)       v = x2[n * 16 + i];
        else if (i == 16) v = mask[n];
        else              v = labels[n * 4 + (i - 17)];
        cin_s[wid][i] = v;
    }
    // same-wave LDS write->read: ordered via lgkmcnt, no barrier needed.
    int k = lane & 31;
    const float* w = (h == 0) ? &Wl_s[k * DIN] : &Wr_s[k * DIN];
    float a2 = (h == 0) ? bl2[k] : br2[k];
#pragma unroll
    for (int i = 0; i < DIN; ++i) a2 += cin_s[wid][i] * w[i];
    if (h == 0) xlh[n * 32 + k] = f2bf(a2);
    else        xr[n * 32 + k]  = a2;
}

// ---------------- conv2 + hidden-update + y1/x1 + dense3 fused -------------
// Full-wave walk -> cell = tanh(.); hn = u*h+(1-u)*cell (hidden updated);
// ft2 = [x1(0..15), mask(16), hn(17..48), labels(49..52)];
// xl3 = ft2@Wl3.T+bl3 (bf16), xr3 = ft2@Wr3.T+br3.

__global__ __launch_bounds__(256) void conv2_ud3_kernel(
        const int* __restrict__ row_ptr, const int* __restrict__ csr_src,
        const unsigned short* __restrict__ xlh, const float* __restrict__ xr,
        const float* __restrict__ att2, const float* __restrict__ bconv2,
        const float* __restrict__ g1, float* __restrict__ hidden,
        const float* __restrict__ x_t, const float* __restrict__ mask,
        const float* __restrict__ labels,
        const float* __restrict__ W1, const float* __restrict__ b1,
        const float* __restrict__ Wl3, const float* __restrict__ bl3,
        const float* __restrict__ Wr3, const float* __restrict__ br3,
        unsigned short* __restrict__ xlh2, float* __restrict__ xr2) {
    __shared__ float Wl_s[WD];
    __shared__ float Wr_s[WD];
    __shared__ float W1_s[FEAT * HID];
    __shared__ float ft2_s[4][DIN + 3];
    __shared__ float hs[4][HID + 1];
    for (int idx = threadIdx.x; idx < WD; idx += 256) {
        Wl_s[idx] = Wl3[idx];
        Wr_s[idx] = Wr3[idx];
    }
    for (int idx = threadIdx.x; idx < FEAT * HID; idx += 256) W1_s[idx] = W1[idx];
    __syncthreads();

    int wid  = threadIdx.x >> 6;
    int lane = threadIdx.x & 63;
    int g = lane >> 2, j = lane & 3;
    int n = blockIdx.x * 4 + wid;
    int c0 = j * 8;
    int beg = row_ptr[n], end = row_ptr[n + 1];

    float at[8], xrv[8];
    {
        float4 a0 = *(const float4*)(att2 + c0);
        float4 a1 = *(const float4*)(att2 + c0 + 4);
        at[0] = a0.x; at[1] = a0.y; at[2] = a0.z; at[3] = a0.w;
        at[4] = a1.x; at[5] = a1.y; at[6] = a1.z; at[7] = a1.w;
        float4 r0 = *(const float4*)(xr + n * 32 + c0);
        float4 r1 = *(const float4*)(xr + n * 32 + c0 + 4);
        xrv[0] = r0.x; xrv[1] = r0.y; xrv[2] = r0.z; xrv[3] = r0.w;
        xrv[4] = r1.x; xrv[5] = r1.y; xrv[6] = r1.z; xrv[7] = r1.w;
    }

    float m = -INFINITY, den = 0.0f, acc[8] = {0, 0, 0, 0, 0, 0, 0, 0};
    for (int p = beg + g; p < end; p += 16) {
        int s = csr_src[p];
        uint4 u = *(const uint4*)(xlh + (size_t)s * 32 + c0);
        float v[8];
        unpack8(u, v);
        float e = edge_score8(v, xrv, at);
        online_update8(e, m, den, acc, v);
    }
    float o[8];
    merge_full(m, den, acc, beg < end, o);

    // cell + hidden update for j-slice (all lanes compute; g==0 writes)
    {
        const float* bc = bconv2 + c0;
        float4 h0 = *(const float4*)(hidden + n * 32 + c0);
        float4 h1 = *(const float4*)(hidden + n * 32 + c0 + 4);
        float hvv[8] = {h0.x, h0.y, h0.z, h0.w, h1.x, h1.y, h1.z, h1.w};
        float4 u0 = *(const float4*)(g1 + n * 32 + c0);
        float4 u1 = *(const float4*)(g1 + n * 32 + c0 + 4);
        float uv[8] = {u0.x, u0.y, u0.z, u0.w, u1.x, u1.y, u1.z, u1.w};
        float hn[8];
#pragma unroll
        for (int i = 0; i < 8; ++i) {
            float cell = tanhf(o[i] + bc[i]);
            hn[i] = uv[i] * hvv[i] + (1.0f - uv[i]) * cell;
        }
        if (g == 0) {
            float* hp = hidden + n * 32 + c0;
            ((float4*)hp)[0] = make_float4(hn[0], hn[1], hn[2], hn[3]);
            ((float4*)hp)[1] = make_float4(hn[4], hn[5], hn[6], hn[7]);
#pragma unroll
            for (int i = 0; i < 8; ++i) {
                hs[wid][c0 + i] = hn[i];
                ft2_s[wid][17 + c0 + i] = hn[i];
            }
        }
    }
    if (lane == 4) ft2_s[wid][16] = mask[n];
    if (lane >= 8 && lane < 12) ft2_s[wid][49 + (lane - 8)] = labels[n * 4 + (lane - 8)];
    if (lane >= 48) {                 // y1 / x1 -> ft2[0..15]
        int f = lane - 48;
        float a = b1[f];
        const float* w1r = &W1_s[f * 32];
#pragma unroll
        for (int c = 0; c < 32; ++c) a += hs[wid][c] * w1r[c];
        ft2_s[wid][f] = (mask[n] > 0.5f) ? x_t[n * 16 + f] : a;
    }
    // same-wave LDS ordering; no barrier needed.
    int k = lane & 31;
    int h2 = lane >> 5;
    const float* w = (h2 == 0) ? &Wl_s[k * DIN] : &Wr_s[k * DIN];
    float a3 = (h2 == 0) ? bl3[k] : br3[k];
#pragma unroll
    for (int i = 0; i < DIN; ++i) a3 += ft2_s[wid][i] * w[i];
    if (h2 == 0) xlh2[n * 32 + k] = f2bf(a3);
    else         xr2[n * 32 + k]  = a3;
}

// ---------------- conv3 + y2/x2/out fused, bf16 gather ---------------------

__global__ __launch_bounds__(256) void conv3_out_kernel(const int* __restrict__ row_ptr,
                                                        const int* __restrict__ csr_src,
                                                        const unsigned short* __restrict__ xlh,
                                                        const float* __restrict__ xr,
                                                        const float* __restrict__ att,
                                                        const float* __restrict__ bconv,
                                                        const float* __restrict__ hidden,
                                                        const float* __restrict__ W2,
                                                        const float* __restrict__ b2,
                                                        const float* __restrict__ x_t,
                                                        const float* __restrict__ mask,
                                                        float* __restrict__ x2,
                                                        float* __restrict__ out_t) {
    __shared__ float W2s[64 * 16];   // transposed [c][f]
    for (int idx = threadIdx.x; idx < 64 * 16; idx += 256) {
        int f = idx & 15, c = idx >> 4;
        W2s[c * 16 + f] = W2[f * 64 + c];
    }
    __syncthreads();

    int wid  = threadIdx.x >> 6;
    int lane = threadIdx.x & 63;
    int g = lane >> 2, j = lane & 3;
    int n = blockIdx.x * 4 + wid;
    int c0 = j * 8;
    int beg = row_ptr[n], end = row_ptr[n + 1];

    float at[8], xrv[8];
    {
        float4 a0 = *(const float4*)(att + c0);
        float4 a1 = *(const float4*)(att + c0 + 4);
        at[0] = a0.x; at[1] = a0.y; at[2] = a0.z; at[3] = a0.w;
        at[4] = a1.x; at[5] = a1.y; at[6] = a1.z; at[7] = a1.w;
        float4 r0 = *(const float4*)(xr + n * 32 + c0);
        float4 r1 = *(const float4*)(xr + n * 32 + c0 + 4);
        xrv[0] = r0.x; xrv[1] = r0.y; xrv[2] = r0.z; xrv[3] = r0.w;
        xrv[4] = r1.x; xrv[5] = r1.y; xrv[6] = r1.z; xrv[7] = r1.w;
    }

    float m = -INFINITY, den = 0.0f, acc[8] = {0, 0, 0, 0, 0, 0, 0, 0};
    for (int p = beg + g; p < end; p += 16) {
        int s = csr_src[p];
        uint4 u = *(const uint4*)(xlh + (size_t)s * 32 + c0);
        float v[8];
        unpack8(u, v);
        float e = edge_score8(v, xrv, at);
        online_update8(e, m, den, acc, v);
    }
    float o[8];
    merge_full(m, den, acc, beg < end, o);

    float r[8], hv[8];
    {
        const float* bc = bconv + c0;
#pragma unroll
        for (int i = 0; i < 8; ++i) r[i] = fmaxf(o[i] + bc[i], 0.0f);
        float4 h0 = *(const float4*)(hidden + n * 32 + c0);
        float4 h1 = *(const float4*)(hidden + n * 32 + c0 + 4);
        hv[0] = h0.x; hv[1] = h0.y; hv[2] = h0.z; hv[3] = h0.w;
        hv[4] = h1.x; hv[5] = h1.y; hv[6] = h1.z; hv[7] = h1.w;
    }

    int f = lane & 15;
    int base = lane & ~3;
    float y = b2[f];
#pragma unroll
    for (int j2 = 0; j2 < 4; ++j2) {
#pragma unroll
        for (int i = 0; i < 8; ++i) {
            float sv = __shfl(r[i], base + j2);
            float hh = __shfl(hv[i], base + j2);
            int c = j2 * 8 + i;
            y += sv * W2s[c * 16 + f] + hh * W2s[(32 + c) * 16 + f];
        }
    }
    if (lane < 16) {
        float mv = mask[n];
        float xv = x_t[n * 16 + f];
        float rr = (mv > 0.5f) ? xv : y;
        x2[n * 16 + f] = rr;
        out_t[n * 16 + f] = rr;
    }
}

// ---------------- launch ----------------

extern "C" void kernel_launch(void* const* d_in, const int* in_sizes, int n_in,
                              void* d_out, int out_size, void* d_ws, size_t ws_size,
                              hipStream_t stream) {
    const float* x      = (const float*)d_in[0];
    const float* mask   = (const float*)d_in[1];
    const float* labels = (const float*)d_in[2];
    const int*   src    = (const int*)d_in[3];
    const int*   dst    = src + EE;
    // d_in[4] = edge_weight: unused by the reference
    const float* Wl    = (const float*)d_in[5];
    const float* bl    = (const float*)d_in[6];
    const float* Wr    = (const float*)d_in[7];
    const float* br    = (const float*)d_in[8];
    const float* att   = (const float*)d_in[9];
    const float* bconv = (const float*)d_in[10];
    const float* W1    = (const float*)d_in[11];
    const float* b1    = (const float*)d_in[12];
    const float* W2    = (const float*)d_in[13];
    const float* b2    = (const float*)d_in[14];
    float* out = (float*)d_out;

    char* ws = (char*)d_ws;
    size_t off = 0;
    auto alloc = [&](size_t bytes) -> void* {
        void* p = ws + off;
        off = (off + bytes + 255) & ~(size_t)255;
        return p;
    };
    int*   row_ptr = (int*)alloc((NN + 1) * sizeof(int));
    int*   deg     = (int*)alloc(NN * sizeof(int));
    int*   csr_src = (int*)alloc(EE * sizeof(int));
    float* hidden  = (float*)alloc(NN * HID * sizeof(float));
    float* x2      = (float*)alloc(NN * FEAT * sizeof(float));
    unsigned short* xl01h = (unsigned short*)alloc(NN * 64 * sizeof(unsigned short));
    float* xr01    = (float*)alloc(NN * 64 * sizeof(float));
    unsigned short* xlh  = (unsigned short*)alloc(NN * 32 * sizeof(unsigned short));
    float* xr      = (float*)alloc(NN * HID * sizeof(float));
    unsigned short* xlh2 = (unsigned short*)alloc(NN * 32 * sizeof(unsigned short));
    float* xr2     = (float*)alloc(NN * HID * sizeof(float));
    float* g1      = (float*)alloc(NN * HID * sizeof(float));  // update gate

    // CSR build (dst identical for every conv); bitonic segment sort
    // canonicalizes csr_src -> bit-deterministic across calls.
    zero_i32<<<(NN + 255) / 256, 256, 0, stream>>>(deg, NN);
    hist_kernel<<<EE / 256, 256, 0, stream>>>(dst, deg);
    scan_kernel<<<1, 1024, 0, stream>>>(deg, row_ptr);
    zero_i32<<<(NN + 255) / 256, 256, 0, stream>>>(deg, NN);
    scatter_kernel<<<EE / 256, 256, 0, stream>>>(src, dst, row_ptr, deg, csr_src);
    sort_kernel<<<NN / 4, 256, 0, stream>>>(row_ptr, csr_src);
    init_kernel<<<NN * HID / 256, 256, 0, stream>>>(x, mask, hidden, x2);

    const int WDc = WD;
    for (int t = 0; t < TT; ++t) {
        const float* xt = x + (size_t)t * NN * FEAT;
        float* out_t = out + (size_t)t * NN * FEAT;
        // gates 0+1 dense (shared input), bf16 xl + f32 xr
        dense01_kernel<<<NN / 32, 256, 0, stream>>>(x2, mask, labels, hidden,
            Wl, bl, Wr, br, xl01h, xr01);
        // gates 0+1 conv + gate-2 dense fused (reset consumed in-kernel)
        conv01_d2_kernel<<<NN / 4, 256, 0, stream>>>(row_ptr, csr_src, xl01h, xr01,
            att, bconv, x2, mask, labels, hidden,
            Wl + 2 * WDc, bl + 2 * HID, Wr + 2 * WDc, br + 2 * HID,
            g1, xlh, xr);
        // gate-2 conv + hidden update + y1/x1 + gate-3 dense fused
        conv2_ud3_kernel<<<NN / 4, 256, 0, stream>>>(row_ptr, csr_src, xlh, xr,
            att + 2 * HID, bconv + 2 * HID, g1, hidden, xt, mask, labels,
            W1, b1, Wl + 3 * WDc, bl + 3 * HID, Wr + 3 * WDc, br + 3 * HID,
            xlh2, xr2);
        // gate-3 conv + y2/x2/out fused
        conv3_out_kernel<<<NN / 4, 256, 0, stream>>>(row_ptr, csr_src, xlh2, xr2,
            att + 3 * HID, bconv + 3 * HID, hidden, W2, b2, xt, mask, x2, out_t);
    }
}